// Round 7
// baseline (431.464 us; speedup 1.0000x reference)
//
#include <hip/hip_runtime.h>

typedef _Float16 f16;
typedef _Float16 f16x4 __attribute__((ext_vector_type(4)));
typedef _Float16 f16x8 __attribute__((ext_vector_type(8)));
typedef float f32x4 __attribute__((ext_vector_type(4)));
typedef unsigned long long u64;

#define B_ 8
#define N_ 8192
#define S_ 2048
#define D1_ 128
#define D2_ 256
#define M_ (B_ * N_)  // 65536 rows

#define XMIN_ (-4.0f)
#define BINW_ 0.125f
#define NBIN_ 64

__device__ __forceinline__ u64 u64min_(u64 a, u64 b) { return a < b ? a : b; }
__device__ __forceinline__ u64 u64max_(u64 a, u64 b) { return a > b ? a : b; }
__device__ __forceinline__ unsigned umin_(unsigned a, unsigned b) { return a < b ? a : b; }
__device__ __forceinline__ unsigned umax_(unsigned a, unsigned b) { return a > b ? a : b; }

__device__ __forceinline__ int bin_of(float x) {
  int b = (int)floorf((x - XMIN_) * 8.0f);
  return b < 0 ? 0 : (b > 63 ? 63 : b);
}

// async global->LDS, 16B per lane. LDS dest is wave-uniform base + lane*16,
// so the LDS layout must be linear in lane order (no padding).
typedef __attribute__((address_space(1))) const unsigned int GUI;
typedef __attribute__((address_space(3))) unsigned int LUI;
__device__ __forceinline__ void gload_lds16(const f16* g, f16* l) {
  __builtin_amdgcn_global_load_lds((GUI*)g, (LUI*)l, 16, 0, 0);
}

// ---------------- weights f32 -> f16 (both in one launch) ----------------
__global__ __launch_bounds__(256) void cvt_weights(const float* __restrict__ w1,
                                                   const float* __restrict__ w2,
                                                   f16* __restrict__ W1h,
                                                   f16* __restrict__ W2h) {
  int i = blockIdx.x * 256 + threadIdx.x;   // grid = 384
  if (i < 256 * 384) W1h[i] = (f16)w1[i];
  if (i < 128 * 256) W2h[i] = (f16)w2[i];
}

// ---------------- points2 [B,256,2048] f32 -> f2t [B,2048,256] f16 ----------------
__global__ __launch_bounds__(256) void pts2_to_f2t(const float* __restrict__ points2,
                                                   f16* __restrict__ f2t) {
  __shared__ float tile[64][65];
  int t = threadIdx.x;
  int g = blockIdx.x;            // 8 * 32 * 4 = 1024
  int b = g >> 7;
  int rem = g & 127;
  int s0 = (rem >> 2) * 64;
  int d0 = (rem & 3) * 64;
  int lane = t & 63, q = t >> 6;
  const float* src = points2 + (size_t)b * D2_ * S_;
  for (int dl = q; dl < 64; dl += 4)
    tile[dl][lane] = src[(size_t)(d0 + dl) * S_ + s0 + lane];
  __syncthreads();
  for (int sl = q; sl < 64; sl += 4)
    f2t[((size_t)b * S_ + s0 + sl) * D2_ + d0 + lane] = (f16)tile[lane][sl];
}

// ---------------- points1 [B,128,8192] f32 -> X1[:, 0:128] f16 ----------------
__global__ __launch_bounds__(256) void pts1_to_x1(const float* __restrict__ points1,
                                                  f16* __restrict__ X1) {
  __shared__ float tile[64][65];
  int t = threadIdx.x;
  int g = blockIdx.x;            // 8 * 128 * 2 = 2048
  int b = g >> 8;
  int rem = g & 255;
  int n0 = (rem >> 1) * 64;
  int c0 = (rem & 1) * 64;
  int lane = t & 63, q = t >> 6;
  const float* src = points1 + (size_t)b * D1_ * N_;
  for (int cl = q; cl < 64; cl += 4)
    tile[cl][lane] = src[(size_t)(c0 + cl) * N_ + n0 + lane];
  __syncthreads();
  for (int nl = q; nl < 64; nl += 4)
    X1[((size_t)b * N_ + n0 + nl) * 384 + c0 + lane] = (f16)tile[lane][nl];
}

// ---------------- counting sorts: blocks 0-7 = candidates, 8-15 = queries ----
__global__ __launch_bounds__(256) void sort_points(const float* __restrict__ xyz1,
                                                   const float* __restrict__ xyz2,
                                                   float4* __restrict__ binned,
                                                   int* __restrict__ binStart,
                                                   float4* __restrict__ qxyz) {
  __shared__ int hist[NBIN_];
  __shared__ int base[NBIN_ + 1];
  int id = blockIdx.x, t = threadIdx.x;   // grid = 16
  if (id < 8) {
    int b = id;
    if (t < NBIN_) hist[t] = 0;
    __syncthreads();
    const float* x2 = xyz2 + (size_t)b * 3 * S_;
    for (int i = t; i < S_; i += 256)
      atomicAdd(&hist[bin_of(x2[i])], 1);
    __syncthreads();
    if (t == 0) {
      int acc = 0;
      for (int k = 0; k < NBIN_; ++k) { base[k] = acc; acc += hist[k]; }
      base[NBIN_] = acc;
    }
    __syncthreads();
    if (t < NBIN_ + 1) binStart[b * (NBIN_ + 1) + t] = base[t];
    __syncthreads();
    for (int i = t; i < S_; i += 256) {
      float x = x2[i], y = x2[S_ + i], z = x2[2 * S_ + i];
      int pos = atomicAdd(&base[bin_of(x)], 1);
      binned[(size_t)b * S_ + pos] = make_float4(x, y, z, __uint_as_float((unsigned)i));
    }
  } else {
    int b = id - 8;
    if (t < NBIN_) hist[t] = 0;
    __syncthreads();
    const float* x1 = xyz1 + (size_t)b * 3 * N_;
    for (int i = t; i < N_; i += 256)
      atomicAdd(&hist[bin_of(x1[i])], 1);
    __syncthreads();
    if (t == 0) {
      int acc = 0;
      for (int k = 0; k < NBIN_; ++k) { base[k] = acc; acc += hist[k]; }
    }
    __syncthreads();
    for (int i = t; i < N_; i += 256) {
      float x = x1[i], y = x1[N_ + i], z = x1[2 * N_ + i];
      int pos = atomicAdd(&base[bin_of(x)], 1);
      qxyz[(size_t)b * N_ + pos] = make_float4(x, y, z, __uint_as_float((unsigned)i));
    }
  }
}

// ---------------- 3-NN: one query per lane, unroll-8 pipelined flat scans ----
// Each lane owns one sorted query and its full top-6 (no candidate split, no
// merge). Phase 1 scans span+-2 bins as one flat segment; one wave-max
// threshold; exact extension range [Ls,Rs] (skipped bin => truncated key of
// every candidate there > wave-max kk[5] >= any lane's final kk[5] => top-6
// set provably unchanged). Unroll-8 with sentinel key 0xFFFFFFFF (no-op
// through the min/max network) keeps 8 ds_read_b128 in flight. Per-lane f64
// rescore of the 6 survivors -> selection identical to the all-f64 kernel.
__global__ __launch_bounds__(256) void knn3(const float4* __restrict__ qxyz,
                                            const float4* __restrict__ binned,
                                            const int* __restrict__ binStart,
                                            int* __restrict__ idx3, float* __restrict__ w3) {
  __shared__ float4 ls[S_];           // 32 KB sorted candidates (x,y,z,orig_idx_bits)
  __shared__ int sBS[NBIN_ + 1];
  int t = threadIdx.x;
  int b = blockIdx.x >> 5;            // grid = 8 * 32 = 256
  int g = blockIdx.x & 31;            // 256 queries per block, one per thread
  for (int i = t; i < S_; i += 256) ls[i] = binned[(size_t)b * S_ + i];
  if (t < NBIN_ + 1) sBS[t] = binStart[b * (NBIN_ + 1) + t];
  __syncthreads();
  float4 qv = qxyz[(size_t)b * N_ + g * 256 + t];
  float px = qv.x, py = qv.y, pz = qv.z;
  float qlo = px, qhi = px;
  #pragma unroll
  for (int d = 1; d < 64; d <<= 1) {
    qlo = fminf(qlo, __shfl_xor(qlo, d, 64));
    qhi = fmaxf(qhi, __shfl_xor(qhi, d, 64));
  }
  unsigned kk[6];
  #pragma unroll
  for (int j = 0; j < 6; ++j) kk[j] = 0xFFFFFFFFu;

  auto scan_seg = [&](int j0, int j1) {
    for (int j = j0; j < j1; j += 8) {
      #pragma unroll
      for (int u = 0; u < 8; ++u) {
        int jj = j + u;
        bool ok = jj < j1;
        float4 q = ls[ok ? jj : j0];   // wave-uniform addr -> broadcast read
        float dx = px - q.x, dy = py - q.y, dz = pz - q.z;
        float d = dx * dx + dy * dy + dz * dz;
        unsigned x = ok ? ((__float_as_uint(d) & 0xFFFFF800u) | (unsigned)jj)
                        : 0xFFFFFFFFu;
        #pragma unroll
        for (int s6 = 0; s6 < 6; ++s6) {
          unsigned hi = umax_(x, kk[s6]);
          kk[s6] = umin_(x, kk[s6]);
          x = hi;
        }
      }
    }
  };

  int blo = bin_of(qlo), bhi = bin_of(qhi);
  int b0 = blo > 2 ? blo - 2 : 0;
  int b1 = bhi < NBIN_ - 3 ? bhi + 2 : NBIN_ - 1;
  scan_seg(sBS[b0], sBS[b1 + 1]);

  unsigned th = kk[5];
  #pragma unroll
  for (int d = 1; d < 64; d <<= 1)
    th = umax_(th, (unsigned)__shfl_xor((int)th, d, 64));

  int Ls = b0;
  while (Ls > 0) {
    float gap = fmaxf(qlo - (XMIN_ + (float)Ls * BINW_), 0.f);
    if ((__float_as_uint(gap * gap) & 0xFFFFF800u) > th) break;
    --Ls;
  }
  int Rs = b1;
  while (Rs < NBIN_ - 1) {
    float gap = fmaxf((XMIN_ + (float)(Rs + 1) * BINW_) - qhi, 0.f);
    if ((__float_as_uint(gap * gap) & 0xFFFFF800u) > th) break;
    ++Rs;
  }
  if (Ls < b0) scan_seg(sBS[Ls], sBS[b0]);
  if (Rs > b1) scan_seg(sBS[b1 + 1], sBS[Rs + 1]);

  // per-lane f64 rescore of the 6 survivors (positions unique by construction)
  double ppx = (double)px, ppy = (double)py, ppz = (double)pz;
  u64 k0 = ~0ull, k1 = ~0ull, k2 = ~0ull;
  #pragma unroll
  for (int i = 0; i < 6; ++i) {
    unsigned si = kk[i] & 0x7FFu;
    float4 q = ls[si];
    double dx = ppx - (double)q.x, dy = ppy - (double)q.y, dz = ppz - (double)q.z;
    double d = dx * dx + dy * dy + dz * dz;
    u64 kb = (__double_as_longlong(d) & 0xFFFFFFFFFFFFF800ull) | (u64)si;
    u64 t1 = u64max_(kb, k0); k0 = u64min_(kb, k0);
    u64 t2 = u64max_(t1, k1); k1 = u64min_(t1, k1);
    k2 = u64min_(t2, k2);
  }
  double d0 = __longlong_as_double((long long)(k0 & 0xFFFFFFFFFFFFF800ull));
  double d1 = __longlong_as_double((long long)(k1 & 0xFFFFFFFFFFFFF800ull));
  double d2 = __longlong_as_double((long long)(k2 & 0xFFFFFFFFFFFFF800ull));
  d0 = d0 > 1e-10 ? d0 : 1e-10;
  d1 = d1 > 1e-10 ? d1 : 1e-10;
  d2 = d2 > 1e-10 ? d2 : 1e-10;
  double w0 = 1.0 / d0, w1 = 1.0 / d1, w2 = 1.0 / d2;
  double inv = 1.0 / (w0 + w1 + w2);
  unsigned p0 = (unsigned)(k0 & 0x7FFull);
  unsigned p1 = (unsigned)(k1 & 0x7FFull);
  unsigned p2 = (unsigned)(k2 & 0x7FFull);
  size_t row = (size_t)b * N_ + g * 256 + t;   // SORTED position -> coalesced
  idx3[row * 3 + 0] = (int)__float_as_uint(ls[p0].w);
  idx3[row * 3 + 1] = (int)__float_as_uint(ls[p1].w);
  idx3[row * 3 + 2] = (int)__float_as_uint(ls[p2].w);
  w3[row * 3 + 0] = (float)(w0 * inv);
  w3[row * 3 + 1] = (float)(w1 * inv);
  w3[row * 3 + 2] = (float)(w2 * inv);
}

// ---------------- gather 3 neighbor rows (sorted order), f16x4 vectorized ----
__global__ __launch_bounds__(256) void gather_interp(const f16* __restrict__ f2t,
                                                     const int* __restrict__ idx3,
                                                     const float* __restrict__ w3,
                                                     const float4* __restrict__ qxyz,
                                                     f16* __restrict__ X1) {
  int t = threadIdx.x;
  int w = t >> 6, lane = t & 63;
  size_t row_s = (size_t)blockIdx.x * 4 + w;   // grid = 16384, sorted position
  int b = (int)(row_s >> 13);
  int orig = (int)__float_as_uint(qxyz[row_s].w);
  int i0 = idx3[row_s * 3], i1 = idx3[row_s * 3 + 1], i2 = idx3[row_s * 3 + 2];
  float w0 = w3[row_s * 3], w1 = w3[row_s * 3 + 1], w2 = w3[row_s * 3 + 2];
  const f16* base = f2t + (size_t)b * S_ * D2_;
  f16x4 a0 = *(const f16x4*)(base + (size_t)i0 * D2_ + lane * 4);
  f16x4 a1 = *(const f16x4*)(base + (size_t)i1 * D2_ + lane * 4);
  f16x4 a2 = *(const f16x4*)(base + (size_t)i2 * D2_ + lane * 4);
  f16x4 o;
  #pragma unroll
  for (int j = 0; j < 4; ++j)
    o[j] = (f16)(w0 * (float)a0[j] + w1 * (float)a1[j] + w2 * (float)a2[j]);
  *(f16x4*)(X1 + ((size_t)b * N_ + orig) * 384 + 128 + lane * 4) = o;
}

// ---------------- GEMM1 fused: Y1[M,256] = X1[M,384] * W1h^T, stats epilogue ----
__global__ __launch_bounds__(256) void gemm1_fused(const f16* __restrict__ A,
                                                   const f16* __restrict__ Bt,
                                                   f16* __restrict__ Y1,
                                                   float* __restrict__ stats) {
  __shared__ __align__(16) f16 sA[128 * 64];   // 16 KB
  __shared__ __align__(16) f16 sB[256 * 64];   // 32 KB
  const int tid = threadIdx.x;
  const int lane = tid & 63;
  const int wave = tid >> 6;
  const int wm = wave & 1, wn = wave >> 1;     // 2x2: wm rows (64), wn col-half (128)
  const int lrow = lane & 15, lq = lane >> 4;
  const size_t row0 = (size_t)blockIdx.x * 128;

  const int srow8 = wave * 8 + (lane >> 3);    // + i*32
  const int kb8 = (lane & 7) * 8;              // halves within 64-half K slice
  const f16* agp = A + (row0 + srow8) * 384 + kb8;
  const f16* bgp = Bt + (size_t)srow8 * 384 + kb8;
  f16* alp = sA + srow8 * 64 + kb8;
  f16* blp = sB + srow8 * 64 + kb8;

  f32x4 acc[4][8] = {};

  for (int k0 = 0; k0 < 384; k0 += 64) {
    __syncthreads();
    #pragma unroll
    for (int i = 0; i < 4; ++i)
      gload_lds16(agp + (size_t)i * 32 * 384 + k0, alp + i * 32 * 64);
    #pragma unroll
    for (int i = 0; i < 8; ++i)
      gload_lds16(bgp + (size_t)i * 32 * 384 + k0, blp + i * 32 * 64);
    __syncthreads();
    #pragma unroll
    for (int kc = 0; kc < 2; ++kc) {
      f16x8 af[4], bf[8];
      #pragma unroll
      for (int mi = 0; mi < 4; ++mi)
        af[mi] = *(const f16x8*)(sA + (wm * 64 + mi * 16 + lrow) * 64 + kc * 32 + lq * 8);
      #pragma unroll
      for (int ni = 0; ni < 8; ++ni)
        bf[ni] = *(const f16x8*)(sB + (wn * 128 + ni * 16 + lrow) * 64 + kc * 32 + lq * 8);
      #pragma unroll
      for (int mi = 0; mi < 4; ++mi)
        #pragma unroll
        for (int ni = 0; ni < 8; ++ni)
          acc[mi][ni] = __builtin_amdgcn_mfma_f32_16x16x32_f16(af[mi], bf[ni], acc[mi][ni], 0, 0, 0);
    }
  }

  #pragma unroll
  for (int mi = 0; mi < 4; ++mi)
    #pragma unroll
    for (int r = 0; r < 4; ++r) {
      size_t row = row0 + wm * 64 + mi * 16 + lq * 4 + r;
      #pragma unroll
      for (int ni = 0; ni < 8; ++ni)
        Y1[row * 256 + wn * 128 + ni * 16 + lrow] = (f16)acc[mi][ni][r];
    }

  #pragma unroll
  for (int ni = 0; ni < 8; ++ni) {
    float s1 = 0.f, s2 = 0.f;
    #pragma unroll
    for (int mi = 0; mi < 4; ++mi)
      #pragma unroll
      for (int r = 0; r < 4; ++r) {
        float v = acc[mi][ni][r];
        s1 += v; s2 += v * v;
      }
    s1 += __shfl_xor(s1, 16, 64);
    s1 += __shfl_xor(s1, 32, 64);
    s2 += __shfl_xor(s2, 16, 64);
    s2 += __shfl_xor(s2, 32, 64);
    if (lane < 16) {
      int col = wn * 128 + ni * 16 + lane;
      atomicAdd(&stats[col], s1);
      atomicAdd(&stats[256 + col], s2);
    }
  }
}

// ---------------- GEMM2 fused: A = ReLU(BN1(Y1)) at staging; Y2 f32 + stats2 ----
__global__ __launch_bounds__(256) void gemm2_fused(const f16* __restrict__ Y1,
                                                   const f16* __restrict__ Bt,
                                                   float* __restrict__ Y2,
                                                   const float* __restrict__ stats,
                                                   const float* __restrict__ g1,
                                                   const float* __restrict__ be1,
                                                   float* __restrict__ stats2) {
  __shared__ __align__(16) f16 sA[128 * 72];
  __shared__ __align__(16) f16 sB[128 * 72];
  __shared__ float s_sc[D2_], s_sh[D2_];
  const int tid = threadIdx.x;
  const int lane = tid & 63;
  const int wave = tid >> 6;
  const int wm = wave & 1, wn = wave >> 1;
  const int lrow = lane & 15, lq = lane >> 4;
  const size_t row0 = (size_t)blockIdx.x * 128;
  const int srow = tid >> 3, scol = tid & 7;

  {
    const float invM = 1.0f / (float)M_;
    float m = stats[tid] * invM;
    float v = stats[D2_ + tid] * invM - m * m;
    float s = rsqrtf(fmaxf(v, 0.f) + 1e-5f) * g1[tid];
    s_sc[tid] = s; s_sh[tid] = be1[tid] - m * s;
  }
  __syncthreads();

  f32x4 acc[4][4] = {};

  for (int k0 = 0; k0 < 256; k0 += 64) {
    float4 sca = *(const float4*)&s_sc[k0 + scol * 8];
    float4 scb = *(const float4*)&s_sc[k0 + scol * 8 + 4];
    float4 sha = *(const float4*)&s_sh[k0 + scol * 8];
    float4 shb = *(const float4*)&s_sh[k0 + scol * 8 + 4];
    __syncthreads();
    #pragma unroll
    for (int i = 0; i < 4; ++i) {
      int r = srow + i * 32;
      f16x8 va = *(const f16x8*)(Y1 + (row0 + r) * 256 + k0 + scol * 8);
      f16x8 ta;
      ta[0] = (f16)fmaxf((float)va[0] * sca.x + sha.x, 0.f);
      ta[1] = (f16)fmaxf((float)va[1] * sca.y + sha.y, 0.f);
      ta[2] = (f16)fmaxf((float)va[2] * sca.z + sha.z, 0.f);
      ta[3] = (f16)fmaxf((float)va[3] * sca.w + sha.w, 0.f);
      ta[4] = (f16)fmaxf((float)va[4] * scb.x + shb.x, 0.f);
      ta[5] = (f16)fmaxf((float)va[5] * scb.y + shb.y, 0.f);
      ta[6] = (f16)fmaxf((float)va[6] * scb.z + shb.z, 0.f);
      ta[7] = (f16)fmaxf((float)va[7] * scb.w + shb.w, 0.f);
      *(f16x8*)(sA + r * 72 + scol * 8) = ta;
      uint4 vb = *(const uint4*)(Bt + (size_t)r * 256 + k0 + scol * 8);
      *(uint4*)(sB + r * 72 + scol * 8) = vb;
    }
    __syncthreads();
    #pragma unroll
    for (int kc = 0; kc < 2; ++kc) {
      f16x8 af[4], bf[4];
      #pragma unroll
      for (int mi = 0; mi < 4; ++mi)
        af[mi] = *(const f16x8*)(sA + (wm * 64 + mi * 16 + lrow) * 72 + kc * 32 + lq * 8);
      #pragma unroll
      for (int ni = 0; ni < 4; ++ni)
        bf[ni] = *(const f16x8*)(sB + (wn * 64 + ni * 16 + lrow) * 72 + kc * 32 + lq * 8);
      #pragma unroll
      for (int mi = 0; mi < 4; ++mi)
        #pragma unroll
        for (int ni = 0; ni < 4; ++ni)
          acc[mi][ni] = __builtin_amdgcn_mfma_f32_16x16x32_f16(af[mi], bf[ni], acc[mi][ni], 0, 0, 0);
    }
  }

  #pragma unroll
  for (int mi = 0; mi < 4; ++mi)
    #pragma unroll
    for (int ni = 0; ni < 4; ++ni)
      #pragma unroll
      for (int r = 0; r < 4; ++r) {
        size_t row = row0 + wm * 64 + mi * 16 + lq * 4 + r;
        int col = wn * 64 + ni * 16 + lrow;
        Y2[row * 128 + col] = acc[mi][ni][r];
      }

  #pragma unroll
  for (int ni = 0; ni < 4; ++ni) {
    float s1 = 0.f, s2 = 0.f;
    #pragma unroll
    for (int mi = 0; mi < 4; ++mi)
      #pragma unroll
      for (int r = 0; r < 4; ++r) {
        float v = acc[mi][ni][r];
        s1 += v; s2 += v * v;
      }
    s1 += __shfl_xor(s1, 16, 64);
    s1 += __shfl_xor(s1, 32, 64);
    s2 += __shfl_xor(s2, 16, 64);
    s2 += __shfl_xor(s2, 32, 64);
    if (lane < 16) {
      int col = wn * 64 + ni * 16 + lane;
      atomicAdd(&stats2[col], s1);
      atomicAdd(&stats2[D1_ + col], s2);
    }
  }
}

// ---------------- BN2 + ReLU + transpose to out [B,128,N] f32 ----------------
__global__ __launch_bounds__(256) void bn2_transpose(const float* __restrict__ Y2,
                                                     float* __restrict__ out,
                                                     const float* __restrict__ stats2,
                                                     const float* __restrict__ g2,
                                                     const float* __restrict__ be2) {
  __shared__ float sc[D1_], sh[D1_];
  __shared__ float tile[64][D1_ + 1];
  int t = threadIdx.x;
  const float invM = 1.0f / (float)M_;
  if (t < D1_) {
    float m = stats2[t] * invM;
    float v = stats2[D1_ + t] * invM - m * m;
    float s = rsqrtf(fmaxf(v, 0.f) + 1e-5f) * g2[t];
    sc[t] = s; sh[t] = be2[t] - m * s;
  }
  __syncthreads();
  int b = blockIdx.x >> 7;            // grid = 1024
  int n0 = (blockIdx.x & 127) * 64;
  const float* src = Y2 + ((size_t)b * N_ + n0) * D1_;
  for (int i = t; i < 64 * D1_; i += 256) {
    int nl = i >> 7, c = i & (D1_ - 1);
    float y = src[(size_t)nl * D1_ + c];
    tile[nl][c] = fmaxf(y * sc[c] + sh[c], 0.f);
  }
  __syncthreads();
  for (int i = t; i < 64 * D1_; i += 256) {
    int c = i >> 6, nl = i & 63;
    out[((size_t)b * D1_ + c) * N_ + n0 + nl] = tile[nl][c];
  }
}

extern "C" void kernel_launch(void* const* d_in, const int* in_sizes, int n_in,
                              void* d_out, int out_size, void* d_ws, size_t ws_size,
                              hipStream_t stream) {
  const float* xyz1    = (const float*)d_in[0];
  const float* xyz2    = (const float*)d_in[1];
  const float* points1 = (const float*)d_in[2];
  const float* points2 = (const float*)d_in[3];
  const float* w1      = (const float*)d_in[4];
  const float* g1      = (const float*)d_in[6];
  const float* be1     = (const float*)d_in[7];
  const float* w2      = (const float*)d_in[8];
  const float* g2      = (const float*)d_in[10];
  const float* be2     = (const float*)d_in[11];
  float* out = (float*)d_out;

  char* ws = (char*)d_ws;
  f16*   f2t   = (f16*)(ws);                  // [B,S,256] f16:   8,388,608 B
  int*   idx3  = (int*)(ws + 8388608);        // [M,3] int:         786,432
  float* w3    = (float*)(ws + 9175040);      // [M,3] f32:         786,432
  f16*   W1h   = (f16*)(ws + 9961472);        // [256,384] f16:     196,608
  f16*   W2h   = (f16*)(ws + 10158080);       // [128,256] f16:      65,536
  float* stats = (float*)(ws + 10223616);     // 768 f32:             4,096
  f16*   X1    = (f16*)(ws + 10227712);       // [M,384] f16: 50,331,648
  f16*   Y1    = (f16*)(ws + 60559360);       // [M,256] f16: 33,554,432
  float* Y2    = (float*)X1;                  // [M,128] f32 reuses X1 (dead after gemm1)
  // knn scratch inside Y1's region (Y1 written only after gather completes)
  float4* binned  = (float4*)(ws + 60559360);            // 8*2048*16 = 262,144
  int* binStart   = (int*)(ws + 60559360 + 262144);      // 8*65*4 (pad to 4KB)
  float4* qxyz    = (float4*)(ws + 60559360 + 266240);   // 8*8192*16 = 1,048,576

  hipMemsetAsync(stats, 0, 768 * sizeof(float), stream);
  cvt_weights<<<384, 256, 0, stream>>>(w1, w2, W1h, W2h);
  pts2_to_f2t<<<1024, 256, 0, stream>>>(points2, f2t);
  sort_points<<<16, 256, 0, stream>>>(xyz1, xyz2, binned, binStart, qxyz);
  knn3<<<256, 256, 0, stream>>>(qxyz, binned, binStart, idx3, w3);
  gather_interp<<<16384, 256, 0, stream>>>(f2t, idx3, w3, qxyz, X1);
  pts1_to_x1<<<2048, 256, 0, stream>>>(points1, X1);
  gemm1_fused<<<512, 256, 0, stream>>>(X1, W1h, Y1, stats);
  gemm2_fused<<<512, 256, 0, stream>>>(Y1, W2h, Y2, stats, g1, be1, stats + 512);
  bn2_transpose<<<1024, 256, 0, stream>>>(Y2, out, stats + 512, g2, be2);
}

// Round 8
// 337.598 us; speedup vs baseline: 1.2780x; 1.2780x over previous
//
#include <hip/hip_runtime.h>

typedef _Float16 f16;
typedef _Float16 f16x4 __attribute__((ext_vector_type(4)));
typedef _Float16 f16x8 __attribute__((ext_vector_type(8)));
typedef float f32x4 __attribute__((ext_vector_type(4)));
typedef unsigned long long u64;

#define B_ 8
#define N_ 8192
#define S_ 2048
#define D1_ 128
#define D2_ 256
#define M_ (B_ * N_)  // 65536 rows

#define XMIN_ (-4.0f)
#define BINW_ 0.125f
#define NBIN_ 64
#define WIN_ 768       // static scan window (bin-snapped), 192 cands/lane after 4-way split

__device__ __forceinline__ u64 u64min_(u64 a, u64 b) { return a < b ? a : b; }
__device__ __forceinline__ u64 u64max_(u64 a, u64 b) { return a > b ? a : b; }
__device__ __forceinline__ unsigned umin_(unsigned a, unsigned b) { return a < b ? a : b; }
__device__ __forceinline__ unsigned umax_(unsigned a, unsigned b) { return a > b ? a : b; }

__device__ __forceinline__ int bin_of(float x) {
  int b = (int)floorf((x - XMIN_) * 8.0f);
  return b < 0 ? 0 : (b > 63 ? 63 : b);
}

// async global->LDS, 16B per lane (wave-uniform base + lane*16; linear layout)
typedef __attribute__((address_space(1))) const unsigned int GUI;
typedef __attribute__((address_space(3))) unsigned int LUI;
__device__ __forceinline__ void gload_lds16(const f16* g, f16* l) {
  __builtin_amdgcn_global_load_lds((GUI*)g, (LUI*)l, 16, 0, 0);
}

// =============== PREP: all independent pre-work in ONE launch ===============
// blocks [0,2048): points1 -> X1[:,0:128]   [2048,3072): points2 -> f2t
// [3072,3088): counting sorts              [3088,3472): weight cvt
// 3472: zero stats
__global__ __launch_bounds__(256) void prep(const float* __restrict__ xyz1,
                                            const float* __restrict__ xyz2,
                                            const float* __restrict__ points1,
                                            const float* __restrict__ points2,
                                            const float* __restrict__ w1,
                                            const float* __restrict__ w2,
                                            f16* __restrict__ X1,
                                            f16* __restrict__ f2t,
                                            f16* __restrict__ W1h,
                                            f16* __restrict__ W2h,
                                            float4* __restrict__ binned,
                                            int* __restrict__ binStart,
                                            float4* __restrict__ qxyz,
                                            float* __restrict__ stats) {
  __shared__ float tile[64][65];
  __shared__ int hist[NBIN_];
  __shared__ int base[NBIN_ + 1];
  int blk = blockIdx.x, t = threadIdx.x;
  int lane = t & 63, q4 = t >> 6;

  if (blk < 2048) {                 // points1 [B,128,8192] -> X1[:,0:128]
    int b = blk >> 8, rem = blk & 255;
    int n0 = (rem >> 1) * 64, c0 = (rem & 1) * 64;
    const float* src = points1 + (size_t)b * D1_ * N_;
    for (int cl = q4; cl < 64; cl += 4)
      tile[cl][lane] = src[(size_t)(c0 + cl) * N_ + n0 + lane];
    __syncthreads();
    for (int nl = q4; nl < 64; nl += 4)
      X1[((size_t)b * N_ + n0 + nl) * 384 + c0 + lane] = (f16)tile[lane][nl];
  } else if (blk < 3072) {          // points2 [B,256,2048] -> f2t [B,2048,256]
    int g = blk - 2048;
    int b = g >> 7, rem = g & 127;
    int s0 = (rem >> 2) * 64, d0 = (rem & 3) * 64;
    const float* src = points2 + (size_t)b * D2_ * S_;
    for (int dl = q4; dl < 64; dl += 4)
      tile[dl][lane] = src[(size_t)(d0 + dl) * S_ + s0 + lane];
    __syncthreads();
    for (int sl = q4; sl < 64; sl += 4)
      f2t[((size_t)b * S_ + s0 + sl) * D2_ + d0 + lane] = (f16)tile[lane][sl];
  } else if (blk < 3088) {          // counting sorts
    int id = blk - 3072;
    if (id < 8) {
      int b = id;
      if (t < NBIN_) hist[t] = 0;
      __syncthreads();
      const float* x2 = xyz2 + (size_t)b * 3 * S_;
      for (int i = t; i < S_; i += 256) atomicAdd(&hist[bin_of(x2[i])], 1);
      __syncthreads();
      if (t == 0) {
        int acc = 0;
        for (int k = 0; k < NBIN_; ++k) { base[k] = acc; acc += hist[k]; }
        base[NBIN_] = acc;
      }
      __syncthreads();
      if (t < NBIN_ + 1) binStart[b * (NBIN_ + 1) + t] = base[t];
      __syncthreads();
      for (int i = t; i < S_; i += 256) {
        float x = x2[i], y = x2[S_ + i], z = x2[2 * S_ + i];
        int pos = atomicAdd(&base[bin_of(x)], 1);
        binned[(size_t)b * S_ + pos] = make_float4(x, y, z, __uint_as_float((unsigned)i));
      }
    } else {
      int b = id - 8;
      if (t < NBIN_) hist[t] = 0;
      __syncthreads();
      const float* x1 = xyz1 + (size_t)b * 3 * N_;
      for (int i = t; i < N_; i += 256) atomicAdd(&hist[bin_of(x1[i])], 1);
      __syncthreads();
      if (t == 0) {
        int acc = 0;
        for (int k = 0; k < NBIN_; ++k) { base[k] = acc; acc += hist[k]; }
      }
      __syncthreads();
      for (int i = t; i < N_; i += 256) {
        float x = x1[i], y = x1[N_ + i], z = x1[2 * N_ + i];
        int pos = atomicAdd(&base[bin_of(x)], 1);
        qxyz[(size_t)b * N_ + pos] = make_float4(x, y, z, __uint_as_float((unsigned)i));
      }
    }
  } else if (blk < 3472) {          // weight cvt
    int i = (blk - 3088) * 256 + t;
    if (i < 256 * 384) W1h[i] = (f16)w1[i];
    if (i < 128 * 256) W2h[i] = (f16)w2[i];
  } else {                          // zero stats (768 f32)
    stats[t] = 0.f; stats[256 + t] = 0.f; stats[512 + t] = 0.f;
  }
}

// =============== 3-NN + gather, fused ===============
// Block = 64 sorted queries, 4 waves split candidates stride-4 (round-4 shape,
// 16 waves/CU). Static 192-iter scan over a bin-snapped 768 window; LDS merge;
// exact bin-edge gap check vs merged wave-max kk[5] (skipped cand's truncated
// key provably > every lane's final kk[5]); rare dynamic extensions + remerge.
// f64 rescore of 6 survivors (identical selection to all-f64 kernel), then the
// block gathers f2t rows and writes X1[:,128:384] directly.
__global__ __launch_bounds__(256) void knn3_gather(const float4* __restrict__ qxyz,
                                                   const float4* __restrict__ binned,
                                                   const int* __restrict__ binStart,
                                                   const f16* __restrict__ f2t,
                                                   f16* __restrict__ X1) {
  __shared__ float4 ls[S_];           // 32 KB (x,y,z,orig_idx_bits)
  __shared__ unsigned ck[6][256];     // 6 KB; aliased as gather table later
  __shared__ int sBS[NBIN_ + 1];
  __shared__ int sFlag;
  int t = threadIdx.x;
  int b = blockIdx.x >> 7;            // grid = 8 * 128
  int g = blockIdx.x & 127;           // 64 queries per block
  for (int i = t; i < S_; i += 256) ls[i] = binned[(size_t)b * S_ + i];
  if (t < NBIN_ + 1) sBS[t] = binStart[b * (NBIN_ + 1) + t];
  __syncthreads();
  int lane = t & 63, w = t >> 6;
  float4 qv = qxyz[(size_t)b * N_ + g * 64 + lane];   // all 4 waves: same 64 queries
  float px = qv.x, py = qv.y, pz = qv.z;
  float qlo = px, qhi = px;
  #pragma unroll
  for (int d = 1; d < 64; d <<= 1) {
    qlo = fminf(qlo, __shfl_xor(qlo, d, 64));
    qhi = fmaxf(qhi, __shfl_xor(qhi, d, 64));
  }
  // bin-snapped static window [ws, ws+WIN_)
  int blo = bin_of(qlo), bhi = bin_of(qhi);
  int cp = (sBS[blo] + sBS[bhi + 1]) >> 1;
  int ws0 = cp - WIN_ / 2;
  if (ws0 < 0) ws0 = 0;
  if (ws0 > S_ - WIN_) ws0 = S_ - WIN_;
  int bL = 0;
  #pragma unroll
  for (int k = 1; k < NBIN_; ++k) bL = (sBS[k] <= ws0) ? k : bL;
  int ws = sBS[bL];
  int we = ws + WIN_;                 // ws <= S_-WIN_ so we <= S_

  unsigned kk[6];
  #pragma unroll
  for (int j = 0; j < 6; ++j) kk[j] = 0xFFFFFFFFu;

  // static scan: 192 candidates per lane, stride 4, shared (broadcast) reads
  {
    int j = ws + w;
    #pragma unroll 8
    for (int it = 0; it < WIN_ / 4; ++it, j += 4) {
      float4 q = ls[j];
      float dx = px - q.x, dy = py - q.y, dz = pz - q.z;
      float d = fmaf(dx, dx, fmaf(dy, dy, dz * dz));
      unsigned x = (__float_as_uint(d) & 0xFFFFF800u) | (unsigned)j;
      #pragma unroll
      for (int s6 = 0; s6 < 6; ++s6) {
        unsigned hi = umax_(x, kk[s6]);
        kk[s6] = umin_(x, kk[s6]);
        x = hi;
      }
    }
  }
  #pragma unroll
  for (int j = 0; j < 6; ++j) ck[j][t] = kk[j];
  __syncthreads();

  unsigned e[6];
  if (t < 64) {
    #pragma unroll
    for (int j = 0; j < 6; ++j) e[j] = ck[j][t];
    #pragma unroll
    for (int ch = 1; ch < 4; ++ch)
      #pragma unroll
      for (int j = 0; j < 6; ++j) {
        unsigned x = ck[j][t + ch * 64];
        #pragma unroll
        for (int jj = 0; jj < 6; ++jj) {
          unsigned hi = umax_(x, e[jj]);
          e[jj] = umin_(x, e[jj]);
          x = hi;
        }
      }
    unsigned th = e[5];
    #pragma unroll
    for (int d = 1; d < 64; d <<= 1)
      th = umax_(th, (unsigned)__shfl_xor((int)th, d, 64));
    bool need = false;
    if (ws > 0) {
      float gl = qlo - (XMIN_ + (float)bL * BINW_);
      if (!(gl > 0.f && (__float_as_uint(gl * gl) & 0xFFFFF800u) > th)) need = true;
    }
    if (we < S_) {
      int bRc = NBIN_ - 1;
      for (int k = 0; k < NBIN_; ++k)
        if (sBS[k + 1] > we) { bRc = k; break; }
      float gr = (XMIN_ + (float)bRc * BINW_) - qhi;
      if (!(gr > 0.f && (__float_as_uint(gr * gr) & 0xFFFFF800u) > th)) need = true;
    }
    if (t == 0) sFlag = need ? 1 : 0;
  }
  __syncthreads();

  if (sFlag) {                        // rare exact fallback: scan the rest
    auto scan_dyn = [&](int j0, int j1) {
      for (int j = j0 + w; j < j1; j += 4) {
        float4 q = ls[j];
        float dx = px - q.x, dy = py - q.y, dz = pz - q.z;
        float d = fmaf(dx, dx, fmaf(dy, dy, dz * dz));
        unsigned x = (__float_as_uint(d) & 0xFFFFF800u) | (unsigned)j;
        #pragma unroll
        for (int s6 = 0; s6 < 6; ++s6) {
          unsigned hi = umax_(x, kk[s6]);
          kk[s6] = umin_(x, kk[s6]);
          x = hi;
        }
      }
    };
    scan_dyn(0, ws);
    scan_dyn(we, S_);
    #pragma unroll
    for (int j = 0; j < 6; ++j) ck[j][t] = kk[j];
  }
  __syncthreads();

  if (t < 64) {
    if (sFlag) {                      // remerge with extensions included
      #pragma unroll
      for (int j = 0; j < 6; ++j) e[j] = ck[j][t];
      #pragma unroll
      for (int ch = 1; ch < 4; ++ch)
        #pragma unroll
        for (int j = 0; j < 6; ++j) {
          unsigned x = ck[j][t + ch * 64];
          #pragma unroll
          for (int jj = 0; jj < 6; ++jj) {
            unsigned hi = umax_(x, e[jj]);
            e[jj] = umin_(x, e[jj]);
            x = hi;
          }
        }
    }
    // f64 rescore of the 6 survivors -> exact ordering + weights
    double ppx = (double)px, ppy = (double)py, ppz = (double)pz;
    u64 k0 = ~0ull, k1 = ~0ull, k2 = ~0ull;
    #pragma unroll
    for (int i = 0; i < 6; ++i) {
      unsigned si = e[i] & 0x7FFu;
      float4 q = ls[si];
      double dx = ppx - (double)q.x, dy = ppy - (double)q.y, dz = ppz - (double)q.z;
      double d = dx * dx + dy * dy + dz * dz;
      u64 kb = (__double_as_longlong(d) & 0xFFFFFFFFFFFFF800ull) | (u64)si;
      u64 t1 = u64max_(kb, k0); k0 = u64min_(kb, k0);
      u64 t2 = u64max_(t1, k1); k1 = u64min_(t1, k1);
      k2 = u64min_(t2, k2);
    }
    double d0 = __longlong_as_double((long long)(k0 & 0xFFFFFFFFFFFFF800ull));
    double d1 = __longlong_as_double((long long)(k1 & 0xFFFFFFFFFFFFF800ull));
    double d2 = __longlong_as_double((long long)(k2 & 0xFFFFFFFFFFFFF800ull));
    d0 = d0 > 1e-10 ? d0 : 1e-10;
    d1 = d1 > 1e-10 ? d1 : 1e-10;
    d2 = d2 > 1e-10 ? d2 : 1e-10;
    double w0 = 1.0 / d0, w1 = 1.0 / d1, w2 = 1.0 / d2;
    double inv = 1.0 / (w0 + w1 + w2);
    unsigned p0 = (unsigned)(k0 & 0x7FFull);
    unsigned p1 = (unsigned)(k1 & 0x7FFull);
    unsigned p2 = (unsigned)(k2 & 0x7FFull);
    unsigned* tab = &ck[0][0];        // alias; barriers order all cross-wave access
    tab[t * 8 + 0] = __float_as_uint(qv.w);
    tab[t * 8 + 1] = __float_as_uint(ls[p0].w);
    tab[t * 8 + 2] = __float_as_uint(ls[p1].w);
    tab[t * 8 + 3] = __float_as_uint(ls[p2].w);
    tab[t * 8 + 4] = __float_as_uint((float)(w0 * inv));
    tab[t * 8 + 5] = __float_as_uint((float)(w1 * inv));
    tab[t * 8 + 6] = __float_as_uint((float)(w2 * inv));
  }
  __syncthreads();

  // gather: wave w handles queries [w*16, w*16+16); 64 lanes x f16x4 = one row
  {
    const unsigned* tab = &ck[0][0];
    const f16* basef = f2t + (size_t)b * S_ * D2_;
    #pragma unroll
    for (int i = 0; i < 16; ++i) {
      int q = w * 16 + i;
      int orig = (int)tab[q * 8 + 0];
      int i0 = (int)tab[q * 8 + 1];
      int i1 = (int)tab[q * 8 + 2];
      int i2 = (int)tab[q * 8 + 3];
      float w0 = __uint_as_float(tab[q * 8 + 4]);
      float w1 = __uint_as_float(tab[q * 8 + 5]);
      float w2 = __uint_as_float(tab[q * 8 + 6]);
      f16x4 a0 = *(const f16x4*)(basef + (size_t)i0 * D2_ + lane * 4);
      f16x4 a1 = *(const f16x4*)(basef + (size_t)i1 * D2_ + lane * 4);
      f16x4 a2 = *(const f16x4*)(basef + (size_t)i2 * D2_ + lane * 4);
      f16x4 o;
      #pragma unroll
      for (int j = 0; j < 4; ++j)
        o[j] = (f16)(w0 * (float)a0[j] + w1 * (float)a1[j] + w2 * (float)a2[j]);
      *(f16x4*)(X1 + ((size_t)b * N_ + orig) * 384 + 128 + lane * 4) = o;
    }
  }
}

// ---------------- GEMM1 fused: Y1[M,256] = X1[M,384] * W1h^T, stats epilogue ----
__global__ __launch_bounds__(256) void gemm1_fused(const f16* __restrict__ A,
                                                   const f16* __restrict__ Bt,
                                                   f16* __restrict__ Y1,
                                                   float* __restrict__ stats) {
  __shared__ __align__(16) f16 sA[128 * 64];   // 16 KB
  __shared__ __align__(16) f16 sB[256 * 64];   // 32 KB
  const int tid = threadIdx.x;
  const int lane = tid & 63;
  const int wave = tid >> 6;
  const int wm = wave & 1, wn = wave >> 1;
  const int lrow = lane & 15, lq = lane >> 4;
  const size_t row0 = (size_t)blockIdx.x * 128;

  const int srow8 = wave * 8 + (lane >> 3);
  const int kb8 = (lane & 7) * 8;
  const f16* agp = A + (row0 + srow8) * 384 + kb8;
  const f16* bgp = Bt + (size_t)srow8 * 384 + kb8;
  f16* alp = sA + srow8 * 64 + kb8;
  f16* blp = sB + srow8 * 64 + kb8;

  f32x4 acc[4][8] = {};

  for (int k0 = 0; k0 < 384; k0 += 64) {
    __syncthreads();
    #pragma unroll
    for (int i = 0; i < 4; ++i)
      gload_lds16(agp + (size_t)i * 32 * 384 + k0, alp + i * 32 * 64);
    #pragma unroll
    for (int i = 0; i < 8; ++i)
      gload_lds16(bgp + (size_t)i * 32 * 384 + k0, blp + i * 32 * 64);
    __syncthreads();
    #pragma unroll
    for (int kc = 0; kc < 2; ++kc) {
      f16x8 af[4], bf[8];
      #pragma unroll
      for (int mi = 0; mi < 4; ++mi)
        af[mi] = *(const f16x8*)(sA + (wm * 64 + mi * 16 + lrow) * 64 + kc * 32 + lq * 8);
      #pragma unroll
      for (int ni = 0; ni < 8; ++ni)
        bf[ni] = *(const f16x8*)(sB + (wn * 128 + ni * 16 + lrow) * 64 + kc * 32 + lq * 8);
      #pragma unroll
      for (int mi = 0; mi < 4; ++mi)
        #pragma unroll
        for (int ni = 0; ni < 8; ++ni)
          acc[mi][ni] = __builtin_amdgcn_mfma_f32_16x16x32_f16(af[mi], bf[ni], acc[mi][ni], 0, 0, 0);
    }
  }

  #pragma unroll
  for (int mi = 0; mi < 4; ++mi)
    #pragma unroll
    for (int r = 0; r < 4; ++r) {
      size_t row = row0 + wm * 64 + mi * 16 + lq * 4 + r;
      #pragma unroll
      for (int ni = 0; ni < 8; ++ni)
        Y1[row * 256 + wn * 128 + ni * 16 + lrow] = (f16)acc[mi][ni][r];
    }

  #pragma unroll
  for (int ni = 0; ni < 8; ++ni) {
    float s1 = 0.f, s2 = 0.f;
    #pragma unroll
    for (int mi = 0; mi < 4; ++mi)
      #pragma unroll
      for (int r = 0; r < 4; ++r) {
        float v = acc[mi][ni][r];
        s1 += v; s2 += v * v;
      }
    s1 += __shfl_xor(s1, 16, 64);
    s1 += __shfl_xor(s1, 32, 64);
    s2 += __shfl_xor(s2, 16, 64);
    s2 += __shfl_xor(s2, 32, 64);
    if (lane < 16) {
      int col = wn * 128 + ni * 16 + lane;
      atomicAdd(&stats[col], s1);
      atomicAdd(&stats[256 + col], s2);
    }
  }
}

// ---------------- GEMM2 fused: A = ReLU(BN1(Y1)) at staging; Y2 f32 + stats2 ----
__global__ __launch_bounds__(256) void gemm2_fused(const f16* __restrict__ Y1,
                                                   const f16* __restrict__ Bt,
                                                   float* __restrict__ Y2,
                                                   const float* __restrict__ stats,
                                                   const float* __restrict__ g1,
                                                   const float* __restrict__ be1,
                                                   float* __restrict__ stats2) {
  __shared__ __align__(16) f16 sA[128 * 72];
  __shared__ __align__(16) f16 sB[128 * 72];
  __shared__ float s_sc[D2_], s_sh[D2_];
  const int tid = threadIdx.x;
  const int lane = tid & 63;
  const int wave = tid >> 6;
  const int wm = wave & 1, wn = wave >> 1;
  const int lrow = lane & 15, lq = lane >> 4;
  const size_t row0 = (size_t)blockIdx.x * 128;
  const int srow = tid >> 3, scol = tid & 7;

  {
    const float invM = 1.0f / (float)M_;
    float m = stats[tid] * invM;
    float v = stats[D2_ + tid] * invM - m * m;
    float s = rsqrtf(fmaxf(v, 0.f) + 1e-5f) * g1[tid];
    s_sc[tid] = s; s_sh[tid] = be1[tid] - m * s;
  }
  __syncthreads();

  f32x4 acc[4][4] = {};

  for (int k0 = 0; k0 < 256; k0 += 64) {
    float4 sca = *(const float4*)&s_sc[k0 + scol * 8];
    float4 scb = *(const float4*)&s_sc[k0 + scol * 8 + 4];
    float4 sha = *(const float4*)&s_sh[k0 + scol * 8];
    float4 shb = *(const float4*)&s_sh[k0 + scol * 8 + 4];
    __syncthreads();
    #pragma unroll
    for (int i = 0; i < 4; ++i) {
      int r = srow + i * 32;
      f16x8 va = *(const f16x8*)(Y1 + (row0 + r) * 256 + k0 + scol * 8);
      f16x8 ta;
      ta[0] = (f16)fmaxf((float)va[0] * sca.x + sha.x, 0.f);
      ta[1] = (f16)fmaxf((float)va[1] * sca.y + sha.y, 0.f);
      ta[2] = (f16)fmaxf((float)va[2] * sca.z + sha.z, 0.f);
      ta[3] = (f16)fmaxf((float)va[3] * sca.w + sha.w, 0.f);
      ta[4] = (f16)fmaxf((float)va[4] * scb.x + shb.x, 0.f);
      ta[5] = (f16)fmaxf((float)va[5] * scb.y + shb.y, 0.f);
      ta[6] = (f16)fmaxf((float)va[6] * scb.z + shb.z, 0.f);
      ta[7] = (f16)fmaxf((float)va[7] * scb.w + shb.w, 0.f);
      *(f16x8*)(sA + r * 72 + scol * 8) = ta;
      uint4 vb = *(const uint4*)(Bt + (size_t)r * 256 + k0 + scol * 8);
      *(uint4*)(sB + r * 72 + scol * 8) = vb;
    }
    __syncthreads();
    #pragma unroll
    for (int kc = 0; kc < 2; ++kc) {
      f16x8 af[4], bf[4];
      #pragma unroll
      for (int mi = 0; mi < 4; ++mi)
        af[mi] = *(const f16x8*)(sA + (wm * 64 + mi * 16 + lrow) * 72 + kc * 32 + lq * 8);
      #pragma unroll
      for (int ni = 0; ni < 4; ++ni)
        bf[ni] = *(const f16x8*)(sB + (wn * 64 + ni * 16 + lrow) * 72 + kc * 32 + lq * 8);
      #pragma unroll
      for (int mi = 0; mi < 4; ++mi)
        #pragma unroll
        for (int ni = 0; ni < 4; ++ni)
          acc[mi][ni] = __builtin_amdgcn_mfma_f32_16x16x32_f16(af[mi], bf[ni], acc[mi][ni], 0, 0, 0);
    }
  }

  #pragma unroll
  for (int mi = 0; mi < 4; ++mi)
    #pragma unroll
    for (int ni = 0; ni < 4; ++ni)
      #pragma unroll
      for (int r = 0; r < 4; ++r) {
        size_t row = row0 + wm * 64 + mi * 16 + lq * 4 + r;
        int col = wn * 64 + ni * 16 + lrow;
        Y2[row * 128 + col] = acc[mi][ni][r];
      }

  #pragma unroll
  for (int ni = 0; ni < 4; ++ni) {
    float s1 = 0.f, s2 = 0.f;
    #pragma unroll
    for (int mi = 0; mi < 4; ++mi)
      #pragma unroll
      for (int r = 0; r < 4; ++r) {
        float v = acc[mi][ni][r];
        s1 += v; s2 += v * v;
      }
    s1 += __shfl_xor(s1, 16, 64);
    s1 += __shfl_xor(s1, 32, 64);
    s2 += __shfl_xor(s2, 16, 64);
    s2 += __shfl_xor(s2, 32, 64);
    if (lane < 16) {
      int col = wn * 64 + ni * 16 + lane;
      atomicAdd(&stats2[col], s1);
      atomicAdd(&stats2[D1_ + col], s2);
    }
  }
}

// ---------------- BN2 + ReLU + transpose to out [B,128,N] f32 ----------------
__global__ __launch_bounds__(256) void bn2_transpose(const float* __restrict__ Y2,
                                                     float* __restrict__ out,
                                                     const float* __restrict__ stats2,
                                                     const float* __restrict__ g2,
                                                     const float* __restrict__ be2) {
  __shared__ float sc[D1_], sh[D1_];
  __shared__ float tile[64][D1_ + 1];
  int t = threadIdx.x;
  const float invM = 1.0f / (float)M_;
  if (t < D1_) {
    float m = stats2[t] * invM;
    float v = stats2[D1_ + t] * invM - m * m;
    float s = rsqrtf(fmaxf(v, 0.f) + 1e-5f) * g2[t];
    sc[t] = s; sh[t] = be2[t] - m * s;
  }
  __syncthreads();
  int b = blockIdx.x >> 7;            // grid = 1024
  int n0 = (blockIdx.x & 127) * 64;
  const float* src = Y2 + ((size_t)b * N_ + n0) * D1_;
  for (int i = t; i < 64 * D1_; i += 256) {
    int nl = i >> 7, c = i & (D1_ - 1);
    float y = src[(size_t)nl * D1_ + c];
    tile[nl][c] = fmaxf(y * sc[c] + sh[c], 0.f);
  }
  __syncthreads();
  for (int i = t; i < 64 * D1_; i += 256) {
    int c = i >> 6, nl = i & 63;
    out[((size_t)b * D1_ + c) * N_ + n0 + nl] = tile[nl][c];
  }
}

extern "C" void kernel_launch(void* const* d_in, const int* in_sizes, int n_in,
                              void* d_out, int out_size, void* d_ws, size_t ws_size,
                              hipStream_t stream) {
  const float* xyz1    = (const float*)d_in[0];
  const float* xyz2    = (const float*)d_in[1];
  const float* points1 = (const float*)d_in[2];
  const float* points2 = (const float*)d_in[3];
  const float* w1      = (const float*)d_in[4];
  const float* g1      = (const float*)d_in[6];
  const float* be1     = (const float*)d_in[7];
  const float* w2      = (const float*)d_in[8];
  const float* g2      = (const float*)d_in[10];
  const float* be2     = (const float*)d_in[11];
  float* out = (float*)d_out;

  char* ws = (char*)d_ws;
  f16*   f2t   = (f16*)(ws);                  // [B,S,256] f16:   8,388,608 B
  f16*   W1h   = (f16*)(ws + 9961472);        // [256,384] f16
  f16*   W2h   = (f16*)(ws + 10158080);       // [128,256] f16
  float* stats = (float*)(ws + 10223616);     // 768 f32
  f16*   X1    = (f16*)(ws + 10227712);       // [M,384] f16
  f16*   Y1    = (f16*)(ws + 60559360);       // [M,256] f16
  float* Y2    = (float*)X1;                  // [M,128] f32 reuses X1
  float4* binned  = (float4*)(ws + 60559360);            // in Y1 region
  int* binStart   = (int*)(ws + 60559360 + 262144);
  float4* qxyz    = (float4*)(ws + 60559360 + 266240);

  prep<<<3473, 256, 0, stream>>>(xyz1, xyz2, points1, points2, w1, w2,
                                 X1, f2t, W1h, W2h, binned, binStart, qxyz, stats);
  knn3_gather<<<1024, 256, 0, stream>>>(qxyz, binned, binStart, f2t, X1);
  gemm1_fused<<<512, 256, 0, stream>>>(X1, W1h, Y1, stats);
  gemm2_fused<<<512, 256, 0, stream>>>(Y1, W2h, Y2, stats, g1, be1, stats + 512);
  bn2_transpose<<<1024, 256, 0, stream>>>(Y2, out, stats + 512, g2, be2);
}

// Round 9
// 316.554 us; speedup vs baseline: 1.3630x; 1.0665x over previous
//
#include <hip/hip_runtime.h>

typedef _Float16 f16;
typedef _Float16 f16x4 __attribute__((ext_vector_type(4)));
typedef _Float16 f16x8 __attribute__((ext_vector_type(8)));
typedef float f32x4 __attribute__((ext_vector_type(4)));
typedef unsigned long long u64;

#define B_ 8
#define N_ 8192
#define S_ 2048
#define D1_ 128
#define D2_ 256
#define M_ (B_ * N_)  // 65536 rows

#define XMIN_ (-4.0f)
#define BINW_ 0.125f
#define NBIN_ 64
#define WIN_ 512       // static scan window (bin-snapped), 128 cands/lane after 4-way split

__device__ __forceinline__ u64 u64min_(u64 a, u64 b) { return a < b ? a : b; }
__device__ __forceinline__ u64 u64max_(u64 a, u64 b) { return a > b ? a : b; }
__device__ __forceinline__ unsigned umin_(unsigned a, unsigned b) { return a < b ? a : b; }
__device__ __forceinline__ unsigned umax_(unsigned a, unsigned b) { return a > b ? a : b; }

__device__ __forceinline__ int bin_of(float x) {
  int b = (int)floorf((x - XMIN_) * 8.0f);
  return b < 0 ? 0 : (b > 63 ? 63 : b);
}

// async global->LDS, 16B per lane (wave-uniform base + lane*16; linear layout)
typedef __attribute__((address_space(1))) const unsigned int GUI;
typedef __attribute__((address_space(3))) unsigned int LUI;
__device__ __forceinline__ void gload_lds16(const f16* g, f16* l) {
  __builtin_amdgcn_global_load_lds((GUI*)g, (LUI*)l, 16, 0, 0);
}

// =============== PREP: all independent pre-work in ONE launch ===============
__global__ __launch_bounds__(256) void prep(const float* __restrict__ xyz1,
                                            const float* __restrict__ xyz2,
                                            const float* __restrict__ points1,
                                            const float* __restrict__ points2,
                                            const float* __restrict__ w1,
                                            const float* __restrict__ w2,
                                            f16* __restrict__ X1,
                                            f16* __restrict__ f2t,
                                            f16* __restrict__ W1h,
                                            f16* __restrict__ W2h,
                                            float4* __restrict__ binned,
                                            int* __restrict__ binStart,
                                            float4* __restrict__ qxyz,
                                            float* __restrict__ stats) {
  __shared__ float tile[64][65];
  __shared__ int hist[NBIN_];
  __shared__ int base[NBIN_ + 1];
  int blk = blockIdx.x, t = threadIdx.x;
  int lane = t & 63, q4 = t >> 6;

  if (blk < 2048) {                 // points1 [B,128,8192] -> X1[:,0:128]
    int b = blk >> 8, rem = blk & 255;
    int n0 = (rem >> 1) * 64, c0 = (rem & 1) * 64;
    const float* src = points1 + (size_t)b * D1_ * N_;
    for (int cl = q4; cl < 64; cl += 4)
      tile[cl][lane] = src[(size_t)(c0 + cl) * N_ + n0 + lane];
    __syncthreads();
    for (int nl = q4; nl < 64; nl += 4)
      X1[((size_t)b * N_ + n0 + nl) * 384 + c0 + lane] = (f16)tile[lane][nl];
  } else if (blk < 3072) {          // points2 [B,256,2048] -> f2t [B,2048,256]
    int g = blk - 2048;
    int b = g >> 7, rem = g & 127;
    int s0 = (rem >> 2) * 64, d0 = (rem & 3) * 64;
    const float* src = points2 + (size_t)b * D2_ * S_;
    for (int dl = q4; dl < 64; dl += 4)
      tile[dl][lane] = src[(size_t)(d0 + dl) * S_ + s0 + lane];
    __syncthreads();
    for (int sl = q4; sl < 64; sl += 4)
      f2t[((size_t)b * S_ + s0 + sl) * D2_ + d0 + lane] = (f16)tile[lane][sl];
  } else if (blk < 3088) {          // counting sorts
    int id = blk - 3072;
    if (id < 8) {
      int b = id;
      if (t < NBIN_) hist[t] = 0;
      __syncthreads();
      const float* x2 = xyz2 + (size_t)b * 3 * S_;
      for (int i = t; i < S_; i += 256) atomicAdd(&hist[bin_of(x2[i])], 1);
      __syncthreads();
      if (t == 0) {
        int acc = 0;
        for (int k = 0; k < NBIN_; ++k) { base[k] = acc; acc += hist[k]; }
        base[NBIN_] = acc;
      }
      __syncthreads();
      if (t < NBIN_ + 1) binStart[b * (NBIN_ + 1) + t] = base[t];
      __syncthreads();
      for (int i = t; i < S_; i += 256) {
        float x = x2[i], y = x2[S_ + i], z = x2[2 * S_ + i];
        int pos = atomicAdd(&base[bin_of(x)], 1);
        binned[(size_t)b * S_ + pos] = make_float4(x, y, z, __uint_as_float((unsigned)i));
      }
    } else {
      int b = id - 8;
      if (t < NBIN_) hist[t] = 0;
      __syncthreads();
      const float* x1 = xyz1 + (size_t)b * 3 * N_;
      for (int i = t; i < N_; i += 256) atomicAdd(&hist[bin_of(x1[i])], 1);
      __syncthreads();
      if (t == 0) {
        int acc = 0;
        for (int k = 0; k < NBIN_; ++k) { base[k] = acc; acc += hist[k]; }
      }
      __syncthreads();
      for (int i = t; i < N_; i += 256) {
        float x = x1[i], y = x1[N_ + i], z = x1[2 * N_ + i];
        int pos = atomicAdd(&base[bin_of(x)], 1);
        qxyz[(size_t)b * N_ + pos] = make_float4(x, y, z, __uint_as_float((unsigned)i));
      }
    }
  } else if (blk < 3472) {          // weight cvt
    int i = (blk - 3088) * 256 + t;
    if (i < 256 * 384) W1h[i] = (f16)w1[i];
    if (i < 128 * 256) W2h[i] = (f16)w2[i];
  } else {                          // zero stats (768 f32)
    stats[t] = 0.f; stats[256 + t] = 0.f; stats[512 + t] = 0.f;
  }
}

// =============== 3-NN + gather, fused; exact INCREMENTAL extensions ===============
// Static 128-iter scan (bin-snapped 512 window, 4-way wave split), LDS merge,
// wave-max threshold; then wave0 walks bin edges outward with the truncated-key
// prune test to get the EXACT extension range [Lbeg,ws) u [we,Rend) — typically
// 0-2 bins, not the whole rest. Remerge only if extensions non-empty. Skipped
// candidates provably have truncated key > every lane's final kk[5] => top-6
// set unchanged => f64 rescore selection identical to the all-f64 kernel.
__global__ __launch_bounds__(256) void knn3_gather(const float4* __restrict__ qxyz,
                                                   const float4* __restrict__ binned,
                                                   const int* __restrict__ binStart,
                                                   const f16* __restrict__ f2t,
                                                   f16* __restrict__ X1) {
  __shared__ float4 ls[S_];           // 32 KB (x,y,z,orig_idx_bits)
  __shared__ unsigned ck[6][256];     // 6 KB; aliased as gather table later
  __shared__ int sBS[NBIN_ + 1];
  __shared__ int sLbeg, sRend;
  int t = threadIdx.x;
  int b = blockIdx.x >> 7;            // grid = 8 * 128
  int g = blockIdx.x & 127;           // 64 queries per block
  for (int i = t; i < S_; i += 256) ls[i] = binned[(size_t)b * S_ + i];
  if (t < NBIN_ + 1) sBS[t] = binStart[b * (NBIN_ + 1) + t];
  __syncthreads();
  int lane = t & 63, w = t >> 6;
  float4 qv = qxyz[(size_t)b * N_ + g * 64 + lane];   // all 4 waves: same 64 queries
  float px = qv.x, py = qv.y, pz = qv.z;
  float qlo = px, qhi = px;
  #pragma unroll
  for (int d = 1; d < 64; d <<= 1) {
    qlo = fminf(qlo, __shfl_xor(qlo, d, 64));
    qhi = fmaxf(qhi, __shfl_xor(qhi, d, 64));
  }
  // bin-snapped static window [ws, we)
  int blo = bin_of(qlo), bhi = bin_of(qhi);
  int cp = (sBS[blo] + sBS[bhi + 1]) >> 1;
  int ws0 = cp - WIN_ / 2;
  if (ws0 < 0) ws0 = 0;
  if (ws0 > S_ - WIN_) ws0 = S_ - WIN_;
  int bL = 0;
  #pragma unroll
  for (int k = 1; k < NBIN_; ++k) bL = (sBS[k] <= ws0) ? k : bL;
  int ws = sBS[bL];
  int we = ws + WIN_;                 // ws <= ws0 <= S_-WIN_  =>  we <= S_

  unsigned kk[6];
  #pragma unroll
  for (int j = 0; j < 6; ++j) kk[j] = 0xFFFFFFFFu;

  // static scan: 128 candidates per lane, stride 4, shared (broadcast) reads
  {
    int j = ws + w;
    #pragma unroll 8
    for (int it = 0; it < WIN_ / 4; ++it, j += 4) {
      float4 q = ls[j];
      float dx = px - q.x, dy = py - q.y, dz = pz - q.z;
      float d = fmaf(dx, dx, fmaf(dy, dy, dz * dz));
      unsigned x = (__float_as_uint(d) & 0xFFFFF800u) | (unsigned)j;
      #pragma unroll
      for (int s6 = 0; s6 < 6; ++s6) {
        unsigned hi = umax_(x, kk[s6]);
        kk[s6] = umin_(x, kk[s6]);
        x = hi;
      }
    }
  }
  #pragma unroll
  for (int j = 0; j < 6; ++j) ck[j][t] = kk[j];
  __syncthreads();

  unsigned e[6];
  if (t < 64) {
    #pragma unroll
    for (int j = 0; j < 6; ++j) e[j] = ck[j][t];
    #pragma unroll
    for (int ch = 1; ch < 4; ++ch)
      #pragma unroll
      for (int j = 0; j < 6; ++j) {
        unsigned x = ck[j][t + ch * 64];
        #pragma unroll
        for (int jj = 0; jj < 6; ++jj) {
          unsigned hi = umax_(x, e[jj]);
          e[jj] = umin_(x, e[jj]);
          x = hi;
        }
      }
    unsigned th = e[5];
    #pragma unroll
    for (int d = 1; d < 64; d <<= 1)
      th = umax_(th, (unsigned)__shfl_xor((int)th, d, 64));
    if (t == 0) {
      // exact left extension: include bins downward while not provably prunable
      int Lbeg = ws;
      for (int k = bL - 1; k >= 0; --k) {
        float gp = qlo - (XMIN_ + (float)(k + 1) * BINW_);   // dist to bin k's upper edge
        if (gp > 0.f && (__float_as_uint(gp * gp) & 0xFFFFF800u) > th) break;
        Lbeg = sBS[k];
      }
      // exact right extension: first the partial bin containing we, then later bins
      int Rend = we;
      if (we < S_) {
        int bRe = NBIN_ - 1;
        for (int k = 0; k < NBIN_; ++k)
          if (sBS[k + 1] > we) { bRe = k; break; }
        for (int k = bRe; k < NBIN_; ++k) {
          float gp = (XMIN_ + (float)k * BINW_) - qhi;       // dist to bin k's lower edge
          if (gp > 0.f && (__float_as_uint(gp * gp) & 0xFFFFF800u) > th) break;
          Rend = sBS[k + 1];
        }
      }
      sLbeg = Lbeg; sRend = Rend;
    }
  }
  __syncthreads();

  int Lbeg = sLbeg, Rend = sRend;
  bool ext = (Lbeg < ws) || (Rend > we);
  if (ext) {
    auto scan_dyn = [&](int j0, int j1) {
      for (int j = j0 + w; j < j1; j += 4) {
        float4 q = ls[j];
        float dx = px - q.x, dy = py - q.y, dz = pz - q.z;
        float d = fmaf(dx, dx, fmaf(dy, dy, dz * dz));
        unsigned x = (__float_as_uint(d) & 0xFFFFF800u) | (unsigned)j;
        #pragma unroll
        for (int s6 = 0; s6 < 6; ++s6) {
          unsigned hi = umax_(x, kk[s6]);
          kk[s6] = umin_(x, kk[s6]);
          x = hi;
        }
      }
    };
    if (Lbeg < ws) scan_dyn(Lbeg, ws);
    if (Rend > we) scan_dyn(we, Rend);
    #pragma unroll
    for (int j = 0; j < 6; ++j) ck[j][t] = kk[j];
  }
  __syncthreads();

  if (t < 64) {
    if (ext) {                       // remerge with extension results
      #pragma unroll
      for (int j = 0; j < 6; ++j) e[j] = ck[j][t];
      #pragma unroll
      for (int ch = 1; ch < 4; ++ch)
        #pragma unroll
        for (int j = 0; j < 6; ++j) {
          unsigned x = ck[j][t + ch * 64];
          #pragma unroll
          for (int jj = 0; jj < 6; ++jj) {
            unsigned hi = umax_(x, e[jj]);
            e[jj] = umin_(x, e[jj]);
            x = hi;
          }
        }
    }
    // f64 rescore of the 6 survivors -> exact ordering + weights
    double ppx = (double)px, ppy = (double)py, ppz = (double)pz;
    u64 k0 = ~0ull, k1 = ~0ull, k2 = ~0ull;
    #pragma unroll
    for (int i = 0; i < 6; ++i) {
      unsigned si = e[i] & 0x7FFu;
      float4 q = ls[si];
      double dx = ppx - (double)q.x, dy = ppy - (double)q.y, dz = ppz - (double)q.z;
      double d = dx * dx + dy * dy + dz * dz;
      u64 kb = (__double_as_longlong(d) & 0xFFFFFFFFFFFFF800ull) | (u64)si;
      u64 t1 = u64max_(kb, k0); k0 = u64min_(kb, k0);
      u64 t2 = u64max_(t1, k1); k1 = u64min_(t1, k1);
      k2 = u64min_(t2, k2);
    }
    double d0 = __longlong_as_double((long long)(k0 & 0xFFFFFFFFFFFFF800ull));
    double d1 = __longlong_as_double((long long)(k1 & 0xFFFFFFFFFFFFF800ull));
    double d2 = __longlong_as_double((long long)(k2 & 0xFFFFFFFFFFFFF800ull));
    d0 = d0 > 1e-10 ? d0 : 1e-10;
    d1 = d1 > 1e-10 ? d1 : 1e-10;
    d2 = d2 > 1e-10 ? d2 : 1e-10;
    double w0 = 1.0 / d0, w1 = 1.0 / d1, w2 = 1.0 / d2;
    double inv = 1.0 / (w0 + w1 + w2);
    unsigned p0 = (unsigned)(k0 & 0x7FFull);
    unsigned p1 = (unsigned)(k1 & 0x7FFull);
    unsigned p2 = (unsigned)(k2 & 0x7FFull);
    unsigned* tab = &ck[0][0];        // alias; barriers order all cross-wave access
    tab[t * 8 + 0] = __float_as_uint(qv.w);
    tab[t * 8 + 1] = __float_as_uint(ls[p0].w);
    tab[t * 8 + 2] = __float_as_uint(ls[p1].w);
    tab[t * 8 + 3] = __float_as_uint(ls[p2].w);
    tab[t * 8 + 4] = __float_as_uint((float)(w0 * inv));
    tab[t * 8 + 5] = __float_as_uint((float)(w1 * inv));
    tab[t * 8 + 6] = __float_as_uint((float)(w2 * inv));
  }
  __syncthreads();

  // gather: wave w handles queries [w*16, w*16+16); 64 lanes x f16x4 = one row
  {
    const unsigned* tab = &ck[0][0];
    const f16* basef = f2t + (size_t)b * S_ * D2_;
    #pragma unroll
    for (int i = 0; i < 16; ++i) {
      int q = w * 16 + i;
      int orig = (int)tab[q * 8 + 0];
      int i0 = (int)tab[q * 8 + 1];
      int i1 = (int)tab[q * 8 + 2];
      int i2 = (int)tab[q * 8 + 3];
      float w0 = __uint_as_float(tab[q * 8 + 4]);
      float w1 = __uint_as_float(tab[q * 8 + 5]);
      float w2 = __uint_as_float(tab[q * 8 + 6]);
      f16x4 a0 = *(const f16x4*)(basef + (size_t)i0 * D2_ + lane * 4);
      f16x4 a1 = *(const f16x4*)(basef + (size_t)i1 * D2_ + lane * 4);
      f16x4 a2 = *(const f16x4*)(basef + (size_t)i2 * D2_ + lane * 4);
      f16x4 o;
      #pragma unroll
      for (int j = 0; j < 4; ++j)
        o[j] = (f16)(w0 * (float)a0[j] + w1 * (float)a1[j] + w2 * (float)a2[j]);
      *(f16x4*)(X1 + ((size_t)b * N_ + orig) * 384 + 128 + lane * 4) = o;
    }
  }
}

// ---------------- GEMM1 fused: Y1[M,256] = X1[M,384] * W1h^T, stats epilogue ----
__global__ __launch_bounds__(256) void gemm1_fused(const f16* __restrict__ A,
                                                   const f16* __restrict__ Bt,
                                                   f16* __restrict__ Y1,
                                                   float* __restrict__ stats) {
  __shared__ __align__(16) f16 sA[128 * 64];   // 16 KB
  __shared__ __align__(16) f16 sB[256 * 64];   // 32 KB
  const int tid = threadIdx.x;
  const int lane = tid & 63;
  const int wave = tid >> 6;
  const int wm = wave & 1, wn = wave >> 1;
  const int lrow = lane & 15, lq = lane >> 4;
  const size_t row0 = (size_t)blockIdx.x * 128;

  const int srow8 = wave * 8 + (lane >> 3);
  const int kb8 = (lane & 7) * 8;
  const f16* agp = A + (row0 + srow8) * 384 + kb8;
  const f16* bgp = Bt + (size_t)srow8 * 384 + kb8;
  f16* alp = sA + srow8 * 64 + kb8;
  f16* blp = sB + srow8 * 64 + kb8;

  f32x4 acc[4][8] = {};

  for (int k0 = 0; k0 < 384; k0 += 64) {
    __syncthreads();
    #pragma unroll
    for (int i = 0; i < 4; ++i)
      gload_lds16(agp + (size_t)i * 32 * 384 + k0, alp + i * 32 * 64);
    #pragma unroll
    for (int i = 0; i < 8; ++i)
      gload_lds16(bgp + (size_t)i * 32 * 384 + k0, blp + i * 32 * 64);
    __syncthreads();
    #pragma unroll
    for (int kc = 0; kc < 2; ++kc) {
      f16x8 af[4], bf[8];
      #pragma unroll
      for (int mi = 0; mi < 4; ++mi)
        af[mi] = *(const f16x8*)(sA + (wm * 64 + mi * 16 + lrow) * 64 + kc * 32 + lq * 8);
      #pragma unroll
      for (int ni = 0; ni < 8; ++ni)
        bf[ni] = *(const f16x8*)(sB + (wn * 128 + ni * 16 + lrow) * 64 + kc * 32 + lq * 8);
      #pragma unroll
      for (int mi = 0; mi < 4; ++mi)
        #pragma unroll
        for (int ni = 0; ni < 8; ++ni)
          acc[mi][ni] = __builtin_amdgcn_mfma_f32_16x16x32_f16(af[mi], bf[ni], acc[mi][ni], 0, 0, 0);
    }
  }

  #pragma unroll
  for (int mi = 0; mi < 4; ++mi)
    #pragma unroll
    for (int r = 0; r < 4; ++r) {
      size_t row = row0 + wm * 64 + mi * 16 + lq * 4 + r;
      #pragma unroll
      for (int ni = 0; ni < 8; ++ni)
        Y1[row * 256 + wn * 128 + ni * 16 + lrow] = (f16)acc[mi][ni][r];
    }

  #pragma unroll
  for (int ni = 0; ni < 8; ++ni) {
    float s1 = 0.f, s2 = 0.f;
    #pragma unroll
    for (int mi = 0; mi < 4; ++mi)
      #pragma unroll
      for (int r = 0; r < 4; ++r) {
        float v = acc[mi][ni][r];
        s1 += v; s2 += v * v;
      }
    s1 += __shfl_xor(s1, 16, 64);
    s1 += __shfl_xor(s1, 32, 64);
    s2 += __shfl_xor(s2, 16, 64);
    s2 += __shfl_xor(s2, 32, 64);
    if (lane < 16) {
      int col = wn * 128 + ni * 16 + lane;
      atomicAdd(&stats[col], s1);
      atomicAdd(&stats[256 + col], s2);
    }
  }
}

// ---------------- GEMM2 fused: A = ReLU(BN1(Y1)) at staging; Y2 f32 + stats2 ----
__global__ __launch_bounds__(256) void gemm2_fused(const f16* __restrict__ Y1,
                                                   const f16* __restrict__ Bt,
                                                   float* __restrict__ Y2,
                                                   const float* __restrict__ stats,
                                                   const float* __restrict__ g1,
                                                   const float* __restrict__ be1,
                                                   float* __restrict__ stats2) {
  __shared__ __align__(16) f16 sA[128 * 72];
  __shared__ __align__(16) f16 sB[128 * 72];
  __shared__ float s_sc[D2_], s_sh[D2_];
  const int tid = threadIdx.x;
  const int lane = tid & 63;
  const int wave = tid >> 6;
  const int wm = wave & 1, wn = wave >> 1;
  const int lrow = lane & 15, lq = lane >> 4;
  const size_t row0 = (size_t)blockIdx.x * 128;
  const int srow = tid >> 3, scol = tid & 7;

  {
    const float invM = 1.0f / (float)M_;
    float m = stats[tid] * invM;
    float v = stats[D2_ + tid] * invM - m * m;
    float s = rsqrtf(fmaxf(v, 0.f) + 1e-5f) * g1[tid];
    s_sc[tid] = s; s_sh[tid] = be1[tid] - m * s;
  }
  __syncthreads();

  f32x4 acc[4][4] = {};

  for (int k0 = 0; k0 < 256; k0 += 64) {
    float4 sca = *(const float4*)&s_sc[k0 + scol * 8];
    float4 scb = *(const float4*)&s_sc[k0 + scol * 8 + 4];
    float4 sha = *(const float4*)&s_sh[k0 + scol * 8];
    float4 shb = *(const float4*)&s_sh[k0 + scol * 8 + 4];
    __syncthreads();
    #pragma unroll
    for (int i = 0; i < 4; ++i) {
      int r = srow + i * 32;
      f16x8 va = *(const f16x8*)(Y1 + (row0 + r) * 256 + k0 + scol * 8);
      f16x8 ta;
      ta[0] = (f16)fmaxf((float)va[0] * sca.x + sha.x, 0.f);
      ta[1] = (f16)fmaxf((float)va[1] * sca.y + sha.y, 0.f);
      ta[2] = (f16)fmaxf((float)va[2] * sca.z + sha.z, 0.f);
      ta[3] = (f16)fmaxf((float)va[3] * sca.w + sha.w, 0.f);
      ta[4] = (f16)fmaxf((float)va[4] * scb.x + shb.x, 0.f);
      ta[5] = (f16)fmaxf((float)va[5] * scb.y + shb.y, 0.f);
      ta[6] = (f16)fmaxf((float)va[6] * scb.z + shb.z, 0.f);
      ta[7] = (f16)fmaxf((float)va[7] * scb.w + shb.w, 0.f);
      *(f16x8*)(sA + r * 72 + scol * 8) = ta;
      uint4 vb = *(const uint4*)(Bt + (size_t)r * 256 + k0 + scol * 8);
      *(uint4*)(sB + r * 72 + scol * 8) = vb;
    }
    __syncthreads();
    #pragma unroll
    for (int kc = 0; kc < 2; ++kc) {
      f16x8 af[4], bf[4];
      #pragma unroll
      for (int mi = 0; mi < 4; ++mi)
        af[mi] = *(const f16x8*)(sA + (wm * 64 + mi * 16 + lrow) * 72 + kc * 32 + lq * 8);
      #pragma unroll
      for (int ni = 0; ni < 4; ++ni)
        bf[ni] = *(const f16x8*)(sB + (wn * 64 + ni * 16 + lrow) * 72 + kc * 32 + lq * 8);
      #pragma unroll
      for (int mi = 0; mi < 4; ++mi)
        #pragma unroll
        for (int ni = 0; ni < 4; ++ni)
          acc[mi][ni] = __builtin_amdgcn_mfma_f32_16x16x32_f16(af[mi], bf[ni], acc[mi][ni], 0, 0, 0);
    }
  }

  #pragma unroll
  for (int mi = 0; mi < 4; ++mi)
    #pragma unroll
    for (int ni = 0; ni < 4; ++ni)
      #pragma unroll
      for (int r = 0; r < 4; ++r) {
        size_t row = row0 + wm * 64 + mi * 16 + lq * 4 + r;
        int col = wn * 64 + ni * 16 + lrow;
        Y2[row * 128 + col] = acc[mi][ni][r];
      }

  #pragma unroll
  for (int ni = 0; ni < 4; ++ni) {
    float s1 = 0.f, s2 = 0.f;
    #pragma unroll
    for (int mi = 0; mi < 4; ++mi)
      #pragma unroll
      for (int r = 0; r < 4; ++r) {
        float v = acc[mi][ni][r];
        s1 += v; s2 += v * v;
      }
    s1 += __shfl_xor(s1, 16, 64);
    s1 += __shfl_xor(s1, 32, 64);
    s2 += __shfl_xor(s2, 16, 64);
    s2 += __shfl_xor(s2, 32, 64);
    if (lane < 16) {
      int col = wn * 64 + ni * 16 + lane;
      atomicAdd(&stats2[col], s1);
      atomicAdd(&stats2[D1_ + col], s2);
    }
  }
}

// ---------------- BN2 + ReLU + transpose to out [B,128,N] f32 ----------------
__global__ __launch_bounds__(256) void bn2_transpose(const float* __restrict__ Y2,
                                                     float* __restrict__ out,
                                                     const float* __restrict__ stats2,
                                                     const float* __restrict__ g2,
                                                     const float* __restrict__ be2) {
  __shared__ float sc[D1_], sh[D1_];
  __shared__ float tile[64][D1_ + 1];
  int t = threadIdx.x;
  const float invM = 1.0f / (float)M_;
  if (t < D1_) {
    float m = stats2[t] * invM;
    float v = stats2[D1_ + t] * invM - m * m;
    float s = rsqrtf(fmaxf(v, 0.f) + 1e-5f) * g2[t];
    sc[t] = s; sh[t] = be2[t] - m * s;
  }
  __syncthreads();
  int b = blockIdx.x >> 7;            // grid = 1024
  int n0 = (blockIdx.x & 127) * 64;
  const float* src = Y2 + ((size_t)b * N_ + n0) * D1_;
  for (int i = t; i < 64 * D1_; i += 256) {
    int nl = i >> 7, c = i & (D1_ - 1);
    float y = src[(size_t)nl * D1_ + c];
    tile[nl][c] = fmaxf(y * sc[c] + sh[c], 0.f);
  }
  __syncthreads();
  for (int i = t; i < 64 * D1_; i += 256) {
    int c = i >> 6, nl = i & 63;
    out[((size_t)b * D1_ + c) * N_ + n0 + nl] = tile[nl][c];
  }
}

extern "C" void kernel_launch(void* const* d_in, const int* in_sizes, int n_in,
                              void* d_out, int out_size, void* d_ws, size_t ws_size,
                              hipStream_t stream) {
  const float* xyz1    = (const float*)d_in[0];
  const float* xyz2    = (const float*)d_in[1];
  const float* points1 = (const float*)d_in[2];
  const float* points2 = (const float*)d_in[3];
  const float* w1      = (const float*)d_in[4];
  const float* g1      = (const float*)d_in[6];
  const float* be1     = (const float*)d_in[7];
  const float* w2      = (const float*)d_in[8];
  const float* g2      = (const float*)d_in[10];
  const float* be2     = (const float*)d_in[11];
  float* out = (float*)d_out;

  char* ws = (char*)d_ws;
  f16*   f2t   = (f16*)(ws);                  // [B,S,256] f16:   8,388,608 B
  f16*   W1h   = (f16*)(ws + 9961472);        // [256,384] f16
  f16*   W2h   = (f16*)(ws + 10158080);       // [128,256] f16
  float* stats = (float*)(ws + 10223616);     // 768 f32
  f16*   X1    = (f16*)(ws + 10227712);       // [M,384] f16
  f16*   Y1    = (f16*)(ws + 60559360);       // [M,256] f16
  float* Y2    = (float*)X1;                  // [M,128] f32 reuses X1
  float4* binned  = (float4*)(ws + 60559360);            // in Y1 region
  int* binStart   = (int*)(ws + 60559360 + 262144);
  float4* qxyz    = (float4*)(ws + 60559360 + 266240);

  prep<<<3473, 256, 0, stream>>>(xyz1, xyz2, points1, points2, w1, w2,
                                 X1, f2t, W1h, W2h, binned, binStart, qxyz, stats);
  knn3_gather<<<1024, 256, 0, stream>>>(qxyz, binned, binStart, f2t, X1);
  gemm1_fused<<<512, 256, 0, stream>>>(X1, W1h, Y1, stats);
  gemm2_fused<<<512, 256, 0, stream>>>(Y1, W2h, Y2, stats, g1, be1, stats + 512);
  bn2_transpose<<<1024, 256, 0, stream>>>(Y2, out, stats + 512, g2, be2);
}